// Round 10
// baseline (221.281 us; speedup 1.0000x reference)
//
#include <hip/hip_runtime.h>
#include <stdint.h>

#define D_MODEL 1024
#define NHEAD 16
#define HDIM 64
#define BATCH 4
#define SEQ 2048
#define BS (BATCH*SEQ)      // 8192 rows
#define NQKV (3*D_MODEL)    // 3072
#define BHEADS (BATCH*NHEAD) // 64

typedef __bf16 bf16x8 __attribute__((ext_vector_type(8)));
typedef __bf16 bf16x2 __attribute__((ext_vector_type(2)));
typedef float f32x4 __attribute__((ext_vector_type(4)));
typedef float f32x2 __attribute__((ext_vector_type(2)));
typedef float f32x16 __attribute__((ext_vector_type(16)));

struct TrueT  { static constexpr bool value = true;  };
struct FalseT { static constexpr bool value = false; };

__device__ __forceinline__ unsigned short f2bf(float f) {
    union { __bf16 b; unsigned short s; } u; u.b = (__bf16)f; return u.s;
}
__device__ __forceinline__ unsigned pack_bf16(float a, float b) {
    f32x2 t; t[0] = a; t[1] = b;
    bf16x2 r = __builtin_convertvector(t, bf16x2);
    union { bf16x2 v; unsigned u; } u; u.v = r; return u.u;
}

typedef __attribute__((address_space(3))) void lds_void_t;
typedef const __attribute__((address_space(1))) void glb_void_t;
__device__ __forceinline__ void gl2lds16(const void* g, void* l) {
    __builtin_amdgcn_global_load_lds((glb_void_t*)g, (lds_void_t*)l, 16, 0, 0);
}

// ---------------- fused prep: x f32->bf16  +  wqkv transpose  +  wproj transpose ----------------
// 1-D grid regions: [0,8192) cvt_x; [8192,8960) wqkv T (48x16); [8960,9216) wproj T (16x16)
__global__ __launch_bounds__(256) void k_prep(const float4* __restrict__ x,
                                              uint2* __restrict__ xbf,
                                              const float* __restrict__ wqkv,
                                              unsigned short* __restrict__ wqkvT,
                                              const float* __restrict__ wproj,
                                              unsigned short* __restrict__ wprojT) {
    __shared__ float tile[64][65];
    const int bid = blockIdx.x, tid = threadIdx.x;
    if (bid < 8192) {
        int i = bid * 256 + tid;
        float4 v = x[i];
        uint2 r;
        r.x = (unsigned)f2bf(v.x) | ((unsigned)f2bf(v.y) << 16);
        r.y = (unsigned)f2bf(v.z) | ((unsigned)f2bf(v.w) << 16);
        xbf[i] = r;
        return;
    }
    const float* in;
    unsigned short* out;
    int ndim, n0, k0;
    if (bid < 8960) {
        int r = bid - 8192;
        in = wqkv; out = wqkvT; ndim = 3072;
        n0 = (r % 48) * 64; k0 = (r / 48) * 64;
    } else {
        int r = bid - 8960;
        in = wproj; out = wprojT; ndim = 1024;
        n0 = (r % 16) * 64; k0 = (r / 16) * 64;
    }
#pragma unroll
    for (int i = 0; i < 16; i++) {
        int f = i * 256 + tid; int rr = f >> 6, c = f & 63;
        tile[rr][c] = in[(size_t)(k0 + rr) * ndim + n0 + c];
    }
    __syncthreads();
#pragma unroll
    for (int i = 0; i < 16; i++) {
        int f = i * 256 + tid; int n = f >> 6, kq = f & 63;
        out[(size_t)(n0 + n) * 1024 + k0 + kq] = f2bf(tile[kq][n]);
    }
}

// ---------------- GEMM: C[M][N] = A[M][1024] * Bt[N][1024]^T (bf16 in, f32 acc) ----------------
// 128x128 tile, 256 thr, 2-barrier K-loop, global_load_lds staging.
// XCD-partitioned swizzle: each XCD owns a contiguous 1/8 of M, walks N fastest.
// MODE 0: qkv epilogue (q/k swapped-operand D + fused LN; v LDS-transpose -> vT).
// MODE 1: plain f32 C write (N = 1024).
template<int MODE>
__global__ __launch_bounds__(256) void k_gemm(const unsigned short* __restrict__ A,
                                              const unsigned short* __restrict__ Bt,
                                              float* __restrict__ Cout,
                                              unsigned short* __restrict__ qo,
                                              unsigned short* __restrict__ ko,
                                              unsigned short* __restrict__ vto,
                                              const float* __restrict__ qg,
                                              const float* __restrict__ qb,
                                              const float* __restrict__ kg,
                                              const float* __restrict__ kb,
                                              int nbx) {
    __shared__ __align__(16) unsigned short smem[16384];   // 32 KB: As | Bs, reused as scratch
    unsigned short* As = smem;            // 128 x 64
    unsigned short* Bs = smem + 8192;     // 128 x 64
    const int tid = threadIdx.x, lane = tid & 63, wid = tid >> 6;
    const int l16 = lane & 15, lq = lane >> 4;
    const int wr = wid >> 1, wc = wid & 1;

    // XCD-partitioned bijective swizzle (nbx % 8 == 0)
    const int ny = gridDim.y;
    const int bid = blockIdx.x + nbx * blockIdx.y;   // dispatch-linear (x fastest)
    const int xcd = bid & 7, idx = bid >> 3;
    const int by = idx % ny;
    const int bx = xcd * (nbx >> 3) + idx / ny;
    const int M0 = bx * 128, N0 = by * 128;

    const int colbase = N0 + wc * 64;          // wave's 64-col strip
    const int which = (MODE == 0) ? (colbase >> 10) : 3;   // 0=q 1=k 2=v

    f32x4 acc[4][4] = {};

    auto kloop = [&](auto SWAPC) {
        constexpr bool SWAP = decltype(SWAPC)::value;
        for (int k0 = 0; k0 < 1024; k0 += 64) {
#pragma unroll
            for (int i = 0; i < 4; i++) {
                int g = i * 256 + tid;
                int r = g >> 3, c = (g & 7) * 8;
                int ldsbase = (i * 256 + wid * 64) * 8;   // wave-uniform
                gl2lds16(A  + (size_t)(M0 + r) * 1024 + k0 + c, &As[ldsbase]);
                gl2lds16(Bt + (size_t)(N0 + r) * 1024 + k0 + c, &Bs[ldsbase]);
            }
            __syncthreads();   // drains vmcnt -> staged data visible
#pragma unroll
            for (int kk = 0; kk < 2; kk++) {
                bf16x8 af[4], bfr[4];
#pragma unroll
                for (int m = 0; m < 4; m++)
                    af[m] = *(const bf16x8*)&As[(wr * 64 + m * 16 + l16) * 64 + kk * 32 + lq * 8];
#pragma unroll
                for (int n = 0; n < 4; n++)
                    bfr[n] = *(const bf16x8*)&Bs[(wc * 64 + n * 16 + l16) * 64 + kk * 32 + lq * 8];
#pragma unroll
                for (int m = 0; m < 4; m++)
#pragma unroll
                    for (int n = 0; n < 4; n++) {
                        if constexpr (SWAP)
                            acc[m][n] = __builtin_amdgcn_mfma_f32_16x16x32_bf16(bfr[n], af[m], acc[m][n], 0, 0, 0);
                        else
                            acc[m][n] = __builtin_amdgcn_mfma_f32_16x16x32_bf16(af[m], bfr[n], acc[m][n], 0, 0, 0);
                    }
            }
            __syncthreads();
        }
    };

    const bool swapped = (MODE == 0) && (which < 2);
    if (swapped) kloop(TrueT{}); else kloop(FalseT{});

    if (MODE == 1) {
#pragma unroll
        for (int m = 0; m < 4; m++)
#pragma unroll
            for (int n = 0; n < 4; n++)
#pragma unroll
                for (int r = 0; r < 4; r++) {
                    int row = M0 + wr * 64 + m * 16 + lq * 4 + r;
                    int col = N0 + wc * 64 + n * 16 + l16;
                    Cout[(size_t)row * 1024 + col] = acc[m][n][r];
                }
        return;
    }

    // ---- MODE 0 epilogue ----
    const int h = (colbase >> 6) & 15;
    const int b = M0 >> 11;
    const int bh = (b << 4) + h;
    const int srow0 = (M0 & 2047) + wr * 64;

    if (which == 2) {
        // v (normal orientation): per-wave LDS transpose (64x64), XOR-swizzled,
        // then coalesced vT[bh][d][s] stores.
        unsigned short* tw = smem + wid * 4096;   // logical [d][s], s-index XOR (d&7)<<3
#pragma unroll
        for (int m = 0; m < 4; m++)
#pragma unroll
            for (int n = 0; n < 4; n++)
#pragma unroll
                for (int r = 0; r < 4; r++) {
                    int s_l = m * 16 + lq * 4 + r;
                    int d = n * 16 + l16;
                    tw[d * 64 + (s_l ^ ((d & 7) << 3))] = f2bf(acc[m][n][r]);
                }
        asm volatile("" ::: "memory");   // order ds_write -> ds_read (same wave, in-order HW)
        unsigned short* vtb = vto + (size_t)bh * 64 * SEQ + srow0;
#pragma unroll
        for (int j = 0; j < 8; j++) {
            int d_r = j * 8 + (lane >> 3);
            int s8 = (lane & 7) * 8;
            bf16x8 val = *(const bf16x8*)&tw[d_r * 64 + (s8 ^ ((d_r & 7) << 3))];
            *(bf16x8*)(vtb + (size_t)d_r * SEQ + s8) = val;
        }
        return;
    }

    // q/k (swapped orientation): acc[m][n] holds D' with s = srow0 + m*16 + l16,
    // d = n*16 + lq*4 + r.  LN over d = in-register (r, n) + shfl over lq.
    unsigned short* outp = which ? ko : qo;
    const float* gp = which ? kg : qg;
    const float* bp = which ? kb : qb;
    const float cs = which ? 1.0f : 0.18033688011112042f;   // log2(e)/8 folded into q
    f32x4 gv[4], bv4[4];
#pragma unroll
    for (int n = 0; n < 4; n++) {
        gv[n]  = *(const f32x4*)(gp + n * 16 + lq * 4);
        bv4[n] = *(const f32x4*)(bp + n * 16 + lq * 4);
    }

#pragma unroll
    for (int m = 0; m < 4; m++) {
        f32x4 t1 = acc[m][0] + acc[m][1] + acc[m][2] + acc[m][3];
        f32x4 t2 = acc[m][0] * acc[m][0] + acc[m][1] * acc[m][1]
                 + acc[m][2] * acc[m][2] + acc[m][3] * acc[m][3];
        float s1 = (t1[0] + t1[1]) + (t1[2] + t1[3]);
        float s2 = (t2[0] + t2[1]) + (t2[2] + t2[3]);
        s1 += __shfl_xor(s1, 16);  s1 += __shfl_xor(s1, 32);
        s2 += __shfl_xor(s2, 16);  s2 += __shfl_xor(s2, 32);
        float mean = s1 * 0.015625f;
        float rstd = rsqrtf(s2 * 0.015625f - mean * mean + 1e-5f);
        int s = srow0 + m * 16 + l16;
        unsigned short* rowp = outp + ((size_t)bh * SEQ + s) * 64;
#pragma unroll
        for (int n = 0; n < 4; n++) {
            ushort4 u4;
            u4.x = f2bf(((acc[m][n][0] - mean) * rstd * gv[n][0] + bv4[n][0]) * cs);
            u4.y = f2bf(((acc[m][n][1] - mean) * rstd * gv[n][1] + bv4[n][1]) * cs);
            u4.z = f2bf(((acc[m][n][2] - mean) * rstd * gv[n][2] + bv4[n][2]) * cs);
            u4.w = f2bf(((acc[m][n][3] - mean) * rstd * gv[n][3] + bv4[n][3]) * cs);
            *(ushort4*)(rowp + n * 16 + lq * 4) = u4;
        }
    }
}

// ---------------- flash attention: 32x32 MFMA, static-max, 8 waves / 512 thr ----------------
// q[bh][s][64] (pre-scaled by log2e/8), k[bh][s][64], vT[bh][d][s] -> aout bf16.
// 8 waves share ONE K/V staging (DS-write per CU halves vs 4-wave blocks); per-wave
// state identical to the proven R7 kernel (32 q rows, VGPR ~64). Static max -12
// folded into QK C-init: P = exp2(sa) directly, no max tracking.
__global__ __launch_bounds__(512) void k_flash(const unsigned short* __restrict__ q,
                                               const unsigned short* __restrict__ k,
                                               const unsigned short* __restrict__ vt,
                                               unsigned short* __restrict__ aout) {
    __shared__ __align__(16) unsigned short Ks[2][64 * 64];
    __shared__ __align__(16) unsigned short Vs[2][64 * 64];
    const int tid = threadIdx.x, lane = tid & 63, wid = tid >> 6;
    const int l32 = lane & 31, hi = lane >> 5;
    const int bh = blockIdx.x;                 // bid%8 = bh%8 -> all q-blocks of a bh on one XCD
    const int q0 = blockIdx.y * 256 + wid * 32;

    const unsigned short* qrow = q + ((size_t)bh * SEQ + q0 + l32) * 64 + hi * 8;
    bf16x8 bq[4];
#pragma unroll
    for (int t = 0; t < 4; t++)
        bq[t] = *(const bf16x8*)(qrow + t * 16);

    // staging: 512 threads cover 512 K-granules + 512 V-granules (1 each)
    const int srow = tid >> 3, gsrc = (tid & 7) ^ (srow & 7);
    const unsigned short* kp = k  + (size_t)bh * SEQ * 64 + (size_t)srow * 64  + gsrc * 8;
    const unsigned short* vp = vt + (size_t)bh * 64 * SEQ + (size_t)srow * SEQ + gsrc * 8;
    const int ldsoff = wid * 512;              // wave-uniform element offset (64 granules/wave)

    gl2lds16(kp, &Ks[0][ldsoff]);
    gl2lds16(vp, &Vs[0][ldsoff]);
    kp += 64 * 64; vp += 64;
    __syncthreads();

    f32x16 o0 = {}, o1 = {};
    float l_run = 0.f;
    const int xs = (l32 & 7);

    f32x16 minit;
#pragma unroll
    for (int r = 0; r < 16; r++) minit[r] = -12.0f;

    for (int t = 0; t < SEQ / 64; t++) {
        const int cur = t & 1;
        if (t + 1 < SEQ / 64) {
            gl2lds16(kp, &Ks[cur ^ 1][ldsoff]);
            gl2lds16(vp, &Vs[cur ^ 1][ldsoff]);
            kp += 64 * 64; vp += 64;
        }

        // S' - 12 via C-init; sa[col q=l32][kv rows]
        f32x16 sa0 = minit, sa1 = minit;
        __builtin_amdgcn_s_setprio(1);
#pragma unroll
        for (int ks = 0; ks < 4; ks++) {
            int gx = (((ks * 2 + hi) ^ xs) * 8);
            bf16x8 ak0 = *(const bf16x8*)&Ks[cur][l32 * 64 + gx];
            bf16x8 ak1 = *(const bf16x8*)&Ks[cur][(32 + l32) * 64 + gx];
            sa0 = __builtin_amdgcn_mfma_f32_32x32x16_bf16(ak0, bq[ks], sa0, 0, 0, 0);
            sa1 = __builtin_amdgcn_mfma_f32_32x32x16_bf16(ak1, bq[ks], sa1, 0, 0, 0);
        }
        __builtin_amdgcn_s_setprio(0);

        // P = exp2(sa) directly (static max)
        f32x16 p0, p1;
#pragma unroll
        for (int r = 0; r < 16; r++) p0[r] = __builtin_amdgcn_exp2f(sa0[r]);
#pragma unroll
        for (int r = 0; r < 16; r++) p1[r] = __builtin_amdgcn_exp2f(sa1[r]);

        // row sum: pairwise vector tree + lane^32 exchange
        f32x16 ts = p0 + p1;
        f32x4 s4;
#pragma unroll
        for (int j = 0; j < 4; j++)
            s4[j] = (ts[j] + ts[j + 4]) + (ts[j + 8] + ts[j + 12]);
        float rs = (s4[0] + s4[1]) + (s4[2] + s4[3]);
        rs += __shfl_xor(rs, 32);
        l_run += rs;

        // P -> PV B-frags: pack bf16 pairs, half-swap lanes via v_permlane32_swap
        union BP { unsigned w[4]; bf16x8 v; };
        BP bpf[4];
#pragma unroll
        for (int ks = 0; ks < 4; ks++) {
            const f32x16& ps = (ks >> 1) ? p1 : p0;
            const int base = (ks & 1) * 8;
            unsigned a0 = pack_bf16(ps[base + 0], ps[base + 1]);
            unsigned a1 = pack_bf16(ps[base + 2], ps[base + 3]);
            unsigned b0 = pack_bf16(ps[base + 4], ps[base + 5]);
            unsigned b1 = pack_bf16(ps[base + 6], ps[base + 7]);
            asm volatile("v_permlane32_swap_b32 %0, %1" : "+v"(a0), "+v"(b0));
            asm volatile("v_permlane32_swap_b32 %0, %1" : "+v"(a1), "+v"(b1));
            bpf[ks].w[0] = a0; bpf[ks].w[1] = a1; bpf[ks].w[2] = b0; bpf[ks].w[3] = b1;
        }

        // O^T += V^T * P   (o0: d 0..31, o1: d 32..63)
        __builtin_amdgcn_s_setprio(1);
#pragma unroll
        for (int ks = 0; ks < 4; ks++) {
            int gx = (((ks * 2 + hi) ^ xs) * 8);
            bf16x8 av0 = *(const bf16x8*)&Vs[cur][l32 * 64 + gx];
            bf16x8 av1 = *(const bf16x8*)&Vs[cur][(32 + l32) * 64 + gx];
            o0 = __builtin_amdgcn_mfma_f32_32x32x16_bf16(av0, bpf[ks].v, o0, 0, 0, 0);
            o1 = __builtin_amdgcn_mfma_f32_32x32x16_bf16(av1, bpf[ks].v, o1, 0, 0, 0);
        }
        __builtin_amdgcn_s_setprio(0);
        __syncthreads();
    }

    float inv = 1.0f / l_run;
    const int b = bh >> 4, h = bh & 15;
    unsigned short* orow = aout + ((size_t)b * SEQ + q0 + l32) * 1024 + h * 64;
#pragma unroll
    for (int dblk = 0; dblk < 2; dblk++) {
        const f32x16& oo = dblk ? o1 : o0;
#pragma unroll
        for (int q2 = 0; q2 < 4; q2++) {
            ushort4 u4;
            u4.x = f2bf(oo[q2 * 4 + 0] * inv);
            u4.y = f2bf(oo[q2 * 4 + 1] * inv);
            u4.z = f2bf(oo[q2 * 4 + 2] * inv);
            u4.w = f2bf(oo[q2 * 4 + 3] * inv);
            *(ushort4*)(orow + dblk * 32 + q2 * 8 + hi * 4) = u4;
        }
    }
}

extern "C" void kernel_launch(void* const* d_in, const int* in_sizes, int n_in,
                              void* d_out, int out_size, void* d_ws, size_t ws_size,
                              hipStream_t stream) {
    const float* x     = (const float*)d_in[0];
    const float* wqkv  = (const float*)d_in[1];
    const float* wproj = (const float*)d_in[2];
    const float* qg    = (const float*)d_in[3];
    const float* qb    = (const float*)d_in[4];
    const float* kg    = (const float*)d_in[5];
    const float* kb    = (const float*)d_in[6];
    float* out = (float*)d_out;

    char* ws = (char*)d_ws;
    unsigned short* xbf    = (unsigned short*)(ws);                       // 16 MB
    unsigned short* wqkvT  = (unsigned short*)(ws + (16llu << 20));       // 6 MB
    unsigned short* wprojT = (unsigned short*)(ws + (22llu << 20));       // 2 MB
    unsigned short* qraw   = (unsigned short*)(ws + (24llu << 20));       // 16 MB
    unsigned short* kraw   = (unsigned short*)(ws + (40llu << 20));       // 16 MB
    unsigned short* vtr    = (unsigned short*)(ws + (56llu << 20));       // 16 MB (vT direct)
    unsigned short* aattn  = (unsigned short*)(ws + (72llu << 20));       // 16 MB (total 88 MB)

    hipLaunchKernelGGL(k_prep, dim3(9216), dim3(256), 0, stream,
                       (const float4*)x, (uint2*)xbf, wqkv, wqkvT, wproj, wprojT);
    hipLaunchKernelGGL((k_gemm<0>), dim3(64, 24), dim3(256), 0, stream, xbf, wqkvT, (float*)nullptr,
                       qraw, kraw, vtr, qg, qb, kg, kb, 64);
    hipLaunchKernelGGL(k_flash, dim3(64, 8), dim3(512), 0, stream, qraw, kraw, vtr, aattn);
    hipLaunchKernelGGL((k_gemm<1>), dim3(64, 8), dim3(256), 0, stream, aattn, wprojT, out,
                       (unsigned short*)nullptr, (unsigned short*)nullptr, (unsigned short*)nullptr,
                       (const float*)nullptr, (const float*)nullptr, (const float*)nullptr,
                       (const float*)nullptr, 64);
}

// Round 11
// 210.418 us; speedup vs baseline: 1.0516x; 1.0516x over previous
//
#include <hip/hip_runtime.h>
#include <stdint.h>

#define D_MODEL 1024
#define NHEAD 16
#define HDIM 64
#define BATCH 4
#define SEQ 2048
#define BS (BATCH*SEQ)      // 8192 rows
#define NQKV (3*D_MODEL)    // 3072
#define BHEADS (BATCH*NHEAD) // 64

typedef __bf16 bf16x8 __attribute__((ext_vector_type(8)));
typedef __bf16 bf16x2 __attribute__((ext_vector_type(2)));
typedef float f32x4 __attribute__((ext_vector_type(4)));
typedef float f32x2 __attribute__((ext_vector_type(2)));
typedef float f32x16 __attribute__((ext_vector_type(16)));

struct TrueT  { static constexpr bool value = true;  };
struct FalseT { static constexpr bool value = false; };

__device__ __forceinline__ unsigned short f2bf(float f) {
    union { __bf16 b; unsigned short s; } u; u.b = (__bf16)f; return u.s;
}
__device__ __forceinline__ unsigned pack_bf16(float a, float b) {
    f32x2 t; t[0] = a; t[1] = b;
    bf16x2 r = __builtin_convertvector(t, bf16x2);
    union { bf16x2 v; unsigned u; } u; u.v = r; return u.u;
}

typedef __attribute__((address_space(3))) void lds_void_t;
typedef const __attribute__((address_space(1))) void glb_void_t;
__device__ __forceinline__ void gl2lds16(const void* g, void* l) {
    __builtin_amdgcn_global_load_lds((glb_void_t*)g, (lds_void_t*)l, 16, 0, 0);
}

// ---------------- fused prep: x f32->bf16  +  wqkv transpose  +  wproj transpose ----------------
// 1-D grid regions: [0,8192) cvt_x; [8192,8960) wqkv T (48x16); [8960,9216) wproj T (16x16)
__global__ __launch_bounds__(256) void k_prep(const float4* __restrict__ x,
                                              uint2* __restrict__ xbf,
                                              const float* __restrict__ wqkv,
                                              unsigned short* __restrict__ wqkvT,
                                              const float* __restrict__ wproj,
                                              unsigned short* __restrict__ wprojT) {
    __shared__ float tile[64][65];
    const int bid = blockIdx.x, tid = threadIdx.x;
    if (bid < 8192) {
        int i = bid * 256 + tid;
        float4 v = x[i];
        uint2 r;
        r.x = (unsigned)f2bf(v.x) | ((unsigned)f2bf(v.y) << 16);
        r.y = (unsigned)f2bf(v.z) | ((unsigned)f2bf(v.w) << 16);
        xbf[i] = r;
        return;
    }
    const float* in;
    unsigned short* out;
    int ndim, n0, k0;
    if (bid < 8960) {
        int r = bid - 8192;
        in = wqkv; out = wqkvT; ndim = 3072;
        n0 = (r % 48) * 64; k0 = (r / 48) * 64;
    } else {
        int r = bid - 8960;
        in = wproj; out = wprojT; ndim = 1024;
        n0 = (r % 16) * 64; k0 = (r / 16) * 64;
    }
#pragma unroll
    for (int i = 0; i < 16; i++) {
        int f = i * 256 + tid; int rr = f >> 6, c = f & 63;
        tile[rr][c] = in[(size_t)(k0 + rr) * ndim + n0 + c];
    }
    __syncthreads();
#pragma unroll
    for (int i = 0; i < 16; i++) {
        int f = i * 256 + tid; int n = f >> 6, kq = f & 63;
        out[(size_t)(n0 + n) * 1024 + k0 + kq] = f2bf(tile[kq][n]);
    }
}

// ---------------- GEMM: C[M][N] = A[M][1024] * Bt[N][1024]^T (bf16 in, f32 acc) ----------------
// 128x128 tile, 256 thr, 2-barrier K-loop, global_load_lds staging.
// XCD-partitioned swizzle: each XCD owns a contiguous 1/8 of M, walks N fastest.
// MODE 0: qkv epilogue (q/k swapped-operand D + fused LN; v LDS-transpose -> vT).
// MODE 1: plain f32 C write (N = 1024).
template<int MODE>
__global__ __launch_bounds__(256) void k_gemm(const unsigned short* __restrict__ A,
                                              const unsigned short* __restrict__ Bt,
                                              float* __restrict__ Cout,
                                              unsigned short* __restrict__ qo,
                                              unsigned short* __restrict__ ko,
                                              unsigned short* __restrict__ vto,
                                              const float* __restrict__ qg,
                                              const float* __restrict__ qb,
                                              const float* __restrict__ kg,
                                              const float* __restrict__ kb,
                                              int nbx) {
    __shared__ __align__(16) unsigned short smem[16384];   // 32 KB: As | Bs, reused as scratch
    unsigned short* As = smem;            // 128 x 64
    unsigned short* Bs = smem + 8192;     // 128 x 64
    const int tid = threadIdx.x, lane = tid & 63, wid = tid >> 6;
    const int l16 = lane & 15, lq = lane >> 4;
    const int wr = wid >> 1, wc = wid & 1;

    // XCD-partitioned bijective swizzle (nbx % 8 == 0)
    const int ny = gridDim.y;
    const int bid = blockIdx.x + nbx * blockIdx.y;   // dispatch-linear (x fastest)
    const int xcd = bid & 7, idx = bid >> 3;
    const int by = idx % ny;
    const int bx = xcd * (nbx >> 3) + idx / ny;
    const int M0 = bx * 128, N0 = by * 128;

    const int colbase = N0 + wc * 64;          // wave's 64-col strip
    const int which = (MODE == 0) ? (colbase >> 10) : 3;   // 0=q 1=k 2=v

    f32x4 acc[4][4] = {};

    auto kloop = [&](auto SWAPC) {
        constexpr bool SWAP = decltype(SWAPC)::value;
        for (int k0 = 0; k0 < 1024; k0 += 64) {
#pragma unroll
            for (int i = 0; i < 4; i++) {
                int g = i * 256 + tid;
                int r = g >> 3, c = (g & 7) * 8;
                int ldsbase = (i * 256 + wid * 64) * 8;   // wave-uniform
                gl2lds16(A  + (size_t)(M0 + r) * 1024 + k0 + c, &As[ldsbase]);
                gl2lds16(Bt + (size_t)(N0 + r) * 1024 + k0 + c, &Bs[ldsbase]);
            }
            __syncthreads();   // drains vmcnt -> staged data visible
#pragma unroll
            for (int kk = 0; kk < 2; kk++) {
                bf16x8 af[4], bfr[4];
#pragma unroll
                for (int m = 0; m < 4; m++)
                    af[m] = *(const bf16x8*)&As[(wr * 64 + m * 16 + l16) * 64 + kk * 32 + lq * 8];
#pragma unroll
                for (int n = 0; n < 4; n++)
                    bfr[n] = *(const bf16x8*)&Bs[(wc * 64 + n * 16 + l16) * 64 + kk * 32 + lq * 8];
#pragma unroll
                for (int m = 0; m < 4; m++)
#pragma unroll
                    for (int n = 0; n < 4; n++) {
                        if constexpr (SWAP)
                            acc[m][n] = __builtin_amdgcn_mfma_f32_16x16x32_bf16(bfr[n], af[m], acc[m][n], 0, 0, 0);
                        else
                            acc[m][n] = __builtin_amdgcn_mfma_f32_16x16x32_bf16(af[m], bfr[n], acc[m][n], 0, 0, 0);
                    }
            }
            __syncthreads();
        }
    };

    const bool swapped = (MODE == 0) && (which < 2);
    if (swapped) kloop(TrueT{}); else kloop(FalseT{});

    if (MODE == 1) {
#pragma unroll
        for (int m = 0; m < 4; m++)
#pragma unroll
            for (int n = 0; n < 4; n++)
#pragma unroll
                for (int r = 0; r < 4; r++) {
                    int row = M0 + wr * 64 + m * 16 + lq * 4 + r;
                    int col = N0 + wc * 64 + n * 16 + l16;
                    Cout[(size_t)row * 1024 + col] = acc[m][n][r];
                }
        return;
    }

    // ---- MODE 0 epilogue ----
    const int h = (colbase >> 6) & 15;
    const int b = M0 >> 11;
    const int bh = (b << 4) + h;
    const int srow0 = (M0 & 2047) + wr * 64;

    if (which == 2) {
        // v (normal orientation): per-wave LDS transpose (64x64), XOR-swizzled,
        // then coalesced vT[bh][d][s] stores.
        unsigned short* tw = smem + wid * 4096;   // logical [d][s], s-index XOR (d&7)<<3
#pragma unroll
        for (int m = 0; m < 4; m++)
#pragma unroll
            for (int n = 0; n < 4; n++)
#pragma unroll
                for (int r = 0; r < 4; r++) {
                    int s_l = m * 16 + lq * 4 + r;
                    int d = n * 16 + l16;
                    tw[d * 64 + (s_l ^ ((d & 7) << 3))] = f2bf(acc[m][n][r]);
                }
        asm volatile("" ::: "memory");   // order ds_write -> ds_read (same wave, in-order HW)
        unsigned short* vtb = vto + (size_t)bh * 64 * SEQ + srow0;
#pragma unroll
        for (int j = 0; j < 8; j++) {
            int d_r = j * 8 + (lane >> 3);
            int s8 = (lane & 7) * 8;
            bf16x8 val = *(const bf16x8*)&tw[d_r * 64 + (s8 ^ ((d_r & 7) << 3))];
            *(bf16x8*)(vtb + (size_t)d_r * SEQ + s8) = val;
        }
        return;
    }

    // q/k (swapped orientation): acc[m][n] holds D' with s = srow0 + m*16 + l16,
    // d = n*16 + lq*4 + r.  LN over d = in-register (r, n) + shfl over lq.
    unsigned short* outp = which ? ko : qo;
    const float* gp = which ? kg : qg;
    const float* bp = which ? kb : qb;
    const float cs = which ? 1.0f : 0.18033688011112042f;   // log2(e)/8 folded into q
    f32x4 gv[4], bv4[4];
#pragma unroll
    for (int n = 0; n < 4; n++) {
        gv[n]  = *(const f32x4*)(gp + n * 16 + lq * 4);
        bv4[n] = *(const f32x4*)(bp + n * 16 + lq * 4);
    }

#pragma unroll
    for (int m = 0; m < 4; m++) {
        f32x4 t1 = acc[m][0] + acc[m][1] + acc[m][2] + acc[m][3];
        f32x4 t2 = acc[m][0] * acc[m][0] + acc[m][1] * acc[m][1]
                 + acc[m][2] * acc[m][2] + acc[m][3] * acc[m][3];
        float s1 = (t1[0] + t1[1]) + (t1[2] + t1[3]);
        float s2 = (t2[0] + t2[1]) + (t2[2] + t2[3]);
        s1 += __shfl_xor(s1, 16);  s1 += __shfl_xor(s1, 32);
        s2 += __shfl_xor(s2, 16);  s2 += __shfl_xor(s2, 32);
        float mean = s1 * 0.015625f;
        float rstd = rsqrtf(s2 * 0.015625f - mean * mean + 1e-5f);
        int s = srow0 + m * 16 + l16;
        unsigned short* rowp = outp + ((size_t)bh * SEQ + s) * 64;
#pragma unroll
        for (int n = 0; n < 4; n++) {
            ushort4 u4;
            u4.x = f2bf(((acc[m][n][0] - mean) * rstd * gv[n][0] + bv4[n][0]) * cs);
            u4.y = f2bf(((acc[m][n][1] - mean) * rstd * gv[n][1] + bv4[n][1]) * cs);
            u4.z = f2bf(((acc[m][n][2] - mean) * rstd * gv[n][2] + bv4[n][2]) * cs);
            u4.w = f2bf(((acc[m][n][3] - mean) * rstd * gv[n][3] + bv4[n][3]) * cs);
            *(ushort4*)(rowp + n * 16 + lq * 4) = u4;
        }
    }
}

// ---------------- flash attention, 32x32 MFMA, STATIC-MAX softmax (R7/R9-proven) ----------------
// q[bh][s][64] (pre-scaled by log2e/8), k[bh][s][64], vT[bh][d][s] -> aout bf16.
// LN'd q,k => exp2-domain scores <= 11.6 < 12. Static max -12 folded into QK C-init:
// P = exp2(sa) directly, P in [2^-24, 1], no max tracking / rescale.
__global__ __launch_bounds__(256, 4) void k_flash(const unsigned short* __restrict__ q,
                                                  const unsigned short* __restrict__ k,
                                                  const unsigned short* __restrict__ vt,
                                                  unsigned short* __restrict__ aout) {
    __shared__ __align__(16) unsigned short Ks[2][64 * 64];
    __shared__ __align__(16) unsigned short Vs[2][64 * 64];
    const int tid = threadIdx.x, lane = tid & 63, wid = tid >> 6;
    const int l32 = lane & 31, hi = lane >> 5;
    const int bh = blockIdx.x;                 // bh fastest -> q-blocks of one bh share an XCD
    const int q0 = blockIdx.y * 128 + wid * 32;

    const unsigned short* qrow = q + ((size_t)bh * SEQ + q0 + l32) * 64 + hi * 8;
    bf16x8 bq[4];
#pragma unroll
    for (int t = 0; t < 4; t++)
        bq[t] = *(const bf16x8*)(qrow + t * 16);

    const unsigned short* kp[2];
    const unsigned short* vp[2];
#pragma unroll
    for (int i = 0; i < 2; i++) {
        int s = i * 256 + tid;
        int row = s >> 3, gsrc = (s & 7) ^ (row & 7);
        kp[i] = k  + (size_t)bh * SEQ * 64 + (size_t)row * 64  + gsrc * 8;
        vp[i] = vt + (size_t)bh * 64 * SEQ + (size_t)row * SEQ + gsrc * 8;
    }
#pragma unroll
    for (int i = 0; i < 2; i++) {
        int ldsoff = (i * 256 + wid * 64) * 8;
        gl2lds16(kp[i], &Ks[0][ldsoff]);
        gl2lds16(vp[i], &Vs[0][ldsoff]);
        kp[i] += 64 * 64; vp[i] += 64;
    }
    __syncthreads();

    f32x16 o0 = {}, o1 = {};
    float l_run = 0.f;
    const int xs = (l32 & 7);

    f32x16 minit;
#pragma unroll
    for (int r = 0; r < 16; r++) minit[r] = -12.0f;

    for (int t = 0; t < SEQ / 64; t++) {
        const int cur = t & 1;
        if (t + 1 < SEQ / 64) {
#pragma unroll
            for (int i = 0; i < 2; i++) {
                int ldsoff = (i * 256 + wid * 64) * 8;
                gl2lds16(kp[i], &Ks[cur ^ 1][ldsoff]);
                gl2lds16(vp[i], &Vs[cur ^ 1][ldsoff]);
                kp[i] += 64 * 64; vp[i] += 64;
            }
        }

        // S' - 12 via C-init; sa[col q=l32][kv rows]
        f32x16 sa0 = minit, sa1 = minit;
        __builtin_amdgcn_s_setprio(1);
#pragma unroll
        for (int ks = 0; ks < 4; ks++) {
            int gx = (((ks * 2 + hi) ^ xs) * 8);
            bf16x8 ak0 = *(const bf16x8*)&Ks[cur][l32 * 64 + gx];
            bf16x8 ak1 = *(const bf16x8*)&Ks[cur][(32 + l32) * 64 + gx];
            sa0 = __builtin_amdgcn_mfma_f32_32x32x16_bf16(ak0, bq[ks], sa0, 0, 0, 0);
            sa1 = __builtin_amdgcn_mfma_f32_32x32x16_bf16(ak1, bq[ks], sa1, 0, 0, 0);
        }
        __builtin_amdgcn_s_setprio(0);

        // P = exp2(sa) directly (static max)
        f32x16 p0, p1;
#pragma unroll
        for (int r = 0; r < 16; r++) p0[r] = __builtin_amdgcn_exp2f(sa0[r]);
#pragma unroll
        for (int r = 0; r < 16; r++) p1[r] = __builtin_amdgcn_exp2f(sa1[r]);

        // row sum: pairwise vector tree + lane^32 exchange
        f32x16 ts = p0 + p1;
        f32x4 s4;
#pragma unroll
        for (int j = 0; j < 4; j++)
            s4[j] = (ts[j] + ts[j + 4]) + (ts[j + 8] + ts[j + 12]);
        float rs = (s4[0] + s4[1]) + (s4[2] + s4[3]);
        rs += __shfl_xor(rs, 32);
        l_run += rs;

        // P -> PV B-frags: pack bf16 pairs, half-swap lanes via v_permlane32_swap
        union BP { unsigned w[4]; bf16x8 v; };
        BP bpf[4];
#pragma unroll
        for (int ks = 0; ks < 4; ks++) {
            const f32x16& ps = (ks >> 1) ? p1 : p0;
            const int base = (ks & 1) * 8;
            unsigned a0 = pack_bf16(ps[base + 0], ps[base + 1]);
            unsigned a1 = pack_bf16(ps[base + 2], ps[base + 3]);
            unsigned b0 = pack_bf16(ps[base + 4], ps[base + 5]);
            unsigned b1 = pack_bf16(ps[base + 6], ps[base + 7]);
            asm volatile("v_permlane32_swap_b32 %0, %1" : "+v"(a0), "+v"(b0));
            asm volatile("v_permlane32_swap_b32 %0, %1" : "+v"(a1), "+v"(b1));
            bpf[ks].w[0] = a0; bpf[ks].w[1] = a1; bpf[ks].w[2] = b0; bpf[ks].w[3] = b1;
        }

        // O^T += V^T * P   (o0: d 0..31, o1: d 32..63)
        __builtin_amdgcn_s_setprio(1);
#pragma unroll
        for (int ks = 0; ks < 4; ks++) {
            int gx = (((ks * 2 + hi) ^ xs) * 8);
            bf16x8 av0 = *(const bf16x8*)&Vs[cur][l32 * 64 + gx];
            bf16x8 av1 = *(const bf16x8*)&Vs[cur][(32 + l32) * 64 + gx];
            o0 = __builtin_amdgcn_mfma_f32_32x32x16_bf16(av0, bpf[ks].v, o0, 0, 0, 0);
            o1 = __builtin_amdgcn_mfma_f32_32x32x16_bf16(av1, bpf[ks].v, o1, 0, 0, 0);
        }
        __builtin_amdgcn_s_setprio(0);
        __syncthreads();
    }

    float inv = 1.0f / l_run;
    const int b = bh >> 4, h = bh & 15;
    unsigned short* orow = aout + ((size_t)b * SEQ + q0 + l32) * 1024 + h * 64;
#pragma unroll
    for (int dblk = 0; dblk < 2; dblk++) {
        const f32x16& oo = dblk ? o1 : o0;
#pragma unroll
        for (int q2 = 0; q2 < 4; q2++) {
            ushort4 u4;
            u4.x = f2bf(oo[q2 * 4 + 0] * inv);
            u4.y = f2bf(oo[q2 * 4 + 1] * inv);
            u4.z = f2bf(oo[q2 * 4 + 2] * inv);
            u4.w = f2bf(oo[q2 * 4 + 3] * inv);
            *(ushort4*)(orow + dblk * 32 + q2 * 8 + hi * 4) = u4;
        }
    }
}

extern "C" void kernel_launch(void* const* d_in, const int* in_sizes, int n_in,
                              void* d_out, int out_size, void* d_ws, size_t ws_size,
                              hipStream_t stream) {
    const float* x     = (const float*)d_in[0];
    const float* wqkv  = (const float*)d_in[1];
    const float* wproj = (const float*)d_in[2];
    const float* qg    = (const float*)d_in[3];
    const float* qb    = (const float*)d_in[4];
    const float* kg    = (const float*)d_in[5];
    const float* kb    = (const float*)d_in[6];
    float* out = (float*)d_out;

    char* ws = (char*)d_ws;
    unsigned short* xbf    = (unsigned short*)(ws);                       // 16 MB
    unsigned short* wqkvT  = (unsigned short*)(ws + (16llu << 20));       // 6 MB
    unsigned short* wprojT = (unsigned short*)(ws + (22llu << 20));       // 2 MB
    unsigned short* qraw   = (unsigned short*)(ws + (24llu << 20));       // 16 MB
    unsigned short* kraw   = (unsigned short*)(ws + (40llu << 20));       // 16 MB
    unsigned short* vtr    = (unsigned short*)(ws + (56llu << 20));       // 16 MB (vT direct)
    unsigned short* aattn  = (unsigned short*)(ws + (72llu << 20));       // 16 MB (total 88 MB)

    hipLaunchKernelGGL(k_prep, dim3(9216), dim3(256), 0, stream,
                       (const float4*)x, (uint2*)xbf, wqkv, wqkvT, wproj, wprojT);
    hipLaunchKernelGGL((k_gemm<0>), dim3(64, 24), dim3(256), 0, stream, xbf, wqkvT, (float*)nullptr,
                       qraw, kraw, vtr, qg, qb, kg, kb, 64);
    hipLaunchKernelGGL(k_flash, dim3(64, 16), dim3(256), 0, stream, qraw, kraw, vtr, aattn);
    hipLaunchKernelGGL((k_gemm<1>), dim3(64, 8), dim3(256), 0, stream, aattn, wprojT, out,
                       (unsigned short*)nullptr, (unsigned short*)nullptr, (unsigned short*)nullptr,
                       (const float*)nullptr, (const float*)nullptr, (const float*)nullptr,
                       (const float*)nullptr, 64);
}